// Round 2
// baseline (433.617 us; speedup 1.0000x reference)
//
#include <hip/hip_runtime.h>
#include <hip/hip_bf16.h>
#include <hip/hip_fp16.h>

// ---------------------------------------------------------------------------
// Multihead attention with flat-reshape head split + mean-threshold mask.
//   B=8 S=1024 D=512 H=8 -> 64 independent attention problems of (1024 x 64);
//   problem (h,b) = 128 consecutive rows of the 8192x512 projected matrix
//   reinterpreted as 1024x64.
// Precision strategy (round 2): the mean-threshold mask is a discontinuity;
//   fp16 scores flip it ~0.3/row -> absmax 6.6e-3 > 6.05e-3 (round-1 result).
//   Q/K path now uses 3-term bf16 split (hi/lo) for BOTH the projection GEMM
//   and QK^T -> fp32-accurate scores (err ~1e-5, flips ~0.02/row).
//   bf16 chosen over fp16 split: fp16-lo of 0.05-scale weights is subnormal
//   (flush risk in MFMA); bf16 has no subnormal issue at these magnitudes.
//   V / P / O / out-GEMM stay fp16 (combined error ~1e-3 absmax).
// ---------------------------------------------------------------------------

typedef _Float16 f16;
typedef __attribute__((ext_vector_type(8))) _Float16 f16x8;
typedef __attribute__((ext_vector_type(8))) short bf16x8;
typedef __attribute__((ext_vector_type(4))) float f32x4;

#define MFMA16(a, b, c) __builtin_amdgcn_mfma_f32_16x16x32_f16((a), (b), (c), 0, 0, 0)
#define MFMAB16(a, b, c) __builtin_amdgcn_mfma_f32_16x16x32_bf16((a), (b), (c), 0, 0, 0)

__constant__ const float kNorm = 0.04419417382415922f;  // 1/sqrt(512)

// float -> (bf16 hi, bf16 lo) with RNE via __float2bfloat16
__device__ __forceinline__ void splitbf(float v, short& h, short& l) {
  unsigned short hu = __bfloat16_as_ushort(__float2bfloat16(v));
  h = (short)hu;
  float hf = __uint_as_float(((unsigned)hu) << 16);
  l = (short)__bfloat16_as_ushort(__float2bfloat16(v - hf));
}

// --------------------------- weight transpose+convert ----------------------
// W [512][512] f32 (k,n) -> WT [512][512] (n,k).  q,k: bf16 hi/lo; v,o: f16.
__global__ void k_wt(const float* __restrict__ w0, const float* __restrict__ w1,
                     const float* __restrict__ w2, const float* __restrict__ w3,
                     short* __restrict__ qh, short* __restrict__ ql,
                     short* __restrict__ kh, short* __restrict__ kl,
                     f16* __restrict__ vt, f16* __restrict__ ot) {
  const float* W;
  switch (blockIdx.z) {
    case 0: W = w0; break;
    case 1: W = w1; break;
    case 2: W = w2; break;
    default: W = w3; break;
  }
  __shared__ float t[32][33];
  int bx = blockIdx.x, by = blockIdx.y;
  int tx = threadIdx.x, ty = threadIdx.y;  // 32 x 8
#pragma unroll
  for (int i = 0; i < 32; i += 8)
    t[ty + i][tx] = W[(size_t)(by * 32 + ty + i) * 512 + bx * 32 + tx];
  __syncthreads();
#pragma unroll
  for (int i = 0; i < 32; i += 8) {
    size_t idx = (size_t)(bx * 32 + ty + i) * 512 + by * 32 + tx;
    float v = t[tx][ty + i];
    if (blockIdx.z < 2) {
      short h, l;
      splitbf(v, h, l);
      if (blockIdx.z == 0) { qh[idx] = h; ql[idx] = l; }
      else { kh[idx] = h; kl[idx] = l; }
    } else {
      if (blockIdx.z == 2) vt[idx] = (f16)v;
      else ot[idx] = (f16)v;
    }
  }
}

// ------------------------- plain fp16 GEMM body ----------------------------
// C[8192][512] = A[8192][512] @ WT^T + bias ; WT is [n][k] f16.
// 128x128 tile, BK=32, 256 threads = 4 waves 2x2, each wave 64x64.
template <typename AT, typename OT>
__device__ __forceinline__ void gemm_body(const AT* __restrict__ A,
                                          const f16* __restrict__ WT,
                                          const float* __restrict__ bias,
                                          OT* __restrict__ C, int m0, int n0) {
  __shared__ f16 As[128][40];  // +8 pad: stride 80B -> ~2-way bank alias (free)
  __shared__ f16 Bs[128][40];
  const int tid = threadIdx.x;
  const int wv = tid >> 6, lane = tid & 63;
  const int wm = wv >> 1, wn = wv & 1;
  const int l15 = lane & 15, lg = lane >> 4;
  const int sr = tid >> 1, sc = (tid & 1) * 16;

  const f32x4 fzero = {0.f, 0.f, 0.f, 0.f};
  f32x4 acc[4][4];
#pragma unroll
  for (int m = 0; m < 4; ++m)
#pragma unroll
    for (int n = 0; n < 4; ++n) acc[m][n] = fzero;

  for (int k0 = 0; k0 < 512; k0 += 32) {
    if constexpr (sizeof(AT) == 4) {  // fp32 source: convert during staging
      const float* src = (const float*)A + (size_t)(m0 + sr) * 512 + k0 + sc;
      float4 a0 = *(const float4*)(src + 0);
      float4 a1 = *(const float4*)(src + 4);
      float4 a2 = *(const float4*)(src + 8);
      float4 a3 = *(const float4*)(src + 12);
      f16* d = &As[sr][sc];
      d[0] = (f16)a0.x; d[1] = (f16)a0.y; d[2] = (f16)a0.z; d[3] = (f16)a0.w;
      d[4] = (f16)a1.x; d[5] = (f16)a1.y; d[6] = (f16)a1.z; d[7] = (f16)a1.w;
      d[8] = (f16)a2.x; d[9] = (f16)a2.y; d[10] = (f16)a2.z; d[11] = (f16)a2.w;
      d[12] = (f16)a3.x; d[13] = (f16)a3.y; d[14] = (f16)a3.z; d[15] = (f16)a3.w;
    } else {
      const f16* src = (const f16*)A + (size_t)(m0 + sr) * 512 + k0 + sc;
      *(f16x8*)&As[sr][sc] = *(const f16x8*)src;
      *(f16x8*)&As[sr][sc + 8] = *(const f16x8*)(src + 8);
    }
    {
      const f16* src = WT + (size_t)(n0 + sr) * 512 + k0 + sc;
      *(f16x8*)&Bs[sr][sc] = *(const f16x8*)src;
      *(f16x8*)&Bs[sr][sc + 8] = *(const f16x8*)(src + 8);
    }
    __syncthreads();
    f16x8 af[4], bf[4];
#pragma unroll
    for (int m = 0; m < 4; ++m)
      af[m] = *(const f16x8*)&As[wm * 64 + m * 16 + l15][lg * 8];
#pragma unroll
    for (int n = 0; n < 4; ++n)
      bf[n] = *(const f16x8*)&Bs[wn * 64 + n * 16 + l15][lg * 8];
#pragma unroll
    for (int m = 0; m < 4; ++m)
#pragma unroll
      for (int n = 0; n < 4; ++n) acc[m][n] = MFMA16(af[m], bf[n], acc[m][n]);
    __syncthreads();
  }
  // D row=(lane>>4)*4+r, col=lane&15 (m89-verified layout)
#pragma unroll
  for (int n = 0; n < 4; ++n) {
    const int col = n0 + wn * 64 + n * 16 + l15;
    const float b = bias[col];
#pragma unroll
    for (int m = 0; m < 4; ++m) {
      const int row = m0 + wm * 64 + m * 16 + lg * 4;
#pragma unroll
      for (int r = 0; r < 4; ++r) {
        float v = acc[m][n][r] + b;
        C[(size_t)(row + r) * 512 + col] = (OT)v;
      }
    }
  }
}

__global__ __launch_bounds__(256) void k_gemm_v(const float* __restrict__ y,
                                                const f16* __restrict__ vwT,
                                                const float* __restrict__ vb,
                                                f16* __restrict__ Vm) {
  gemm_body<float, f16>(y, vwT, vb, Vm, blockIdx.y * 128, blockIdx.x * 128);
}

__global__ __launch_bounds__(256) void k_gemm_out(const f16* __restrict__ Om,
                                                  const f16* __restrict__ owT,
                                                  const float* __restrict__ ob,
                                                  float* __restrict__ out) {
  gemm_body<f16, float>(Om, owT, ob, out, blockIdx.y * 128, blockIdx.x * 128);
}

// -------------------- split-bf16 GEMM for Q,K projections ------------------
// C = A @ W + b computed as Ah@Wh + Ah@Wl + Al@Wh (fp32 MFMA accum).
// Output written as (hi, lo) bf16 pair for the split QK^T downstream.
__global__ __launch_bounds__(256) void k_gemm_qk(
    const float* __restrict__ x, const float* __restrict__ y,
    const short* __restrict__ qwh, const short* __restrict__ qwl,
    const short* __restrict__ kwh, const short* __restrict__ kwl,
    const float* __restrict__ qb, const float* __restrict__ kbias,
    short* __restrict__ Qh, short* __restrict__ Ql, short* __restrict__ Kh,
    short* __restrict__ Kl) {
  const float* A;
  const short *Wh, *Wl;
  const float* bias;
  short *Ch, *Cl;
  if (blockIdx.z == 0) { A = x; Wh = qwh; Wl = qwl; bias = qb; Ch = Qh; Cl = Ql; }
  else { A = y; Wh = kwh; Wl = kwl; bias = kbias; Ch = Kh; Cl = Kl; }
  const int m0 = blockIdx.y * 128, n0 = blockIdx.x * 128;

  __shared__ short Ah[128][40], Al[128][40];  // 40 KB total LDS
  __shared__ short Bh[128][40], Bl[128][40];
  const int tid = threadIdx.x;
  const int wv = tid >> 6, lane = tid & 63;
  const int wm = wv >> 1, wn = wv & 1;
  const int l15 = lane & 15, lg = lane >> 4;
  const int sr = tid >> 1, sc = (tid & 1) * 16;

  const f32x4 fzero = {0.f, 0.f, 0.f, 0.f};
  f32x4 acc[4][4];
#pragma unroll
  for (int m = 0; m < 4; ++m)
#pragma unroll
    for (int n = 0; n < 4; ++n) acc[m][n] = fzero;

  for (int k0 = 0; k0 < 512; k0 += 32) {
    {
      const float* src = A + (size_t)(m0 + sr) * 512 + k0 + sc;
      float4 a0 = *(const float4*)(src + 0);
      float4 a1 = *(const float4*)(src + 4);
      float4 a2 = *(const float4*)(src + 8);
      float4 a3 = *(const float4*)(src + 12);
      short* dh = &Ah[sr][sc];
      short* dl = &Al[sr][sc];
      splitbf(a0.x, dh[0], dl[0]);   splitbf(a0.y, dh[1], dl[1]);
      splitbf(a0.z, dh[2], dl[2]);   splitbf(a0.w, dh[3], dl[3]);
      splitbf(a1.x, dh[4], dl[4]);   splitbf(a1.y, dh[5], dl[5]);
      splitbf(a1.z, dh[6], dl[6]);   splitbf(a1.w, dh[7], dl[7]);
      splitbf(a2.x, dh[8], dl[8]);   splitbf(a2.y, dh[9], dl[9]);
      splitbf(a2.z, dh[10], dl[10]); splitbf(a2.w, dh[11], dl[11]);
      splitbf(a3.x, dh[12], dl[12]); splitbf(a3.y, dh[13], dl[13]);
      splitbf(a3.z, dh[14], dl[14]); splitbf(a3.w, dh[15], dl[15]);
    }
    {
      const size_t o = (size_t)(n0 + sr) * 512 + k0 + sc;
      *(bf16x8*)&Bh[sr][sc] = *(const bf16x8*)(Wh + o);
      *(bf16x8*)&Bh[sr][sc + 8] = *(const bf16x8*)(Wh + o + 8);
      *(bf16x8*)&Bl[sr][sc] = *(const bf16x8*)(Wl + o);
      *(bf16x8*)&Bl[sr][sc + 8] = *(const bf16x8*)(Wl + o + 8);
    }
    __syncthreads();
    bf16x8 afh[4], afl[4], bfh[4], bfl[4];
#pragma unroll
    for (int m = 0; m < 4; ++m) {
      afh[m] = *(const bf16x8*)&Ah[wm * 64 + m * 16 + l15][lg * 8];
      afl[m] = *(const bf16x8*)&Al[wm * 64 + m * 16 + l15][lg * 8];
    }
#pragma unroll
    for (int n = 0; n < 4; ++n) {
      bfh[n] = *(const bf16x8*)&Bh[wn * 64 + n * 16 + l15][lg * 8];
      bfl[n] = *(const bf16x8*)&Bl[wn * 64 + n * 16 + l15][lg * 8];
    }
#pragma unroll
    for (int m = 0; m < 4; ++m)
#pragma unroll
      for (int n = 0; n < 4; ++n) {
        acc[m][n] = MFMAB16(afh[m], bfh[n], acc[m][n]);
        acc[m][n] = MFMAB16(afh[m], bfl[n], acc[m][n]);
        acc[m][n] = MFMAB16(afl[m], bfh[n], acc[m][n]);
      }
    __syncthreads();
  }
#pragma unroll
  for (int n = 0; n < 4; ++n) {
    const int col = n0 + wn * 64 + n * 16 + l15;
    const float b = bias[col];
#pragma unroll
    for (int m = 0; m < 4; ++m) {
      const int row = m0 + wm * 64 + m * 16 + lg * 4;
#pragma unroll
      for (int r = 0; r < 4; ++r) {
        float v = acc[m][n][r] + b;
        short h, l;
        splitbf(v, h, l);
        const size_t idx = (size_t)(row + r) * 512 + col;
        Ch[idx] = h;
        Cl[idx] = l;
      }
    }
  }
}

// ------------------------------- attention ---------------------------------
// grid (64 q-tiles, 64 problems), 256 threads = 4 waves.
// Phase 1: wave w computes S[16 q][256 keys] via split-bf16 MFMA (6/tile),
//   fragments straight from global (K chunk is L2-resident).
// Softmax: mean-threshold mask; global row max (max > mean always kept).
// Phase 2: P@V fp16, wave w owns output dims [w*16, w*16+16).
__global__ __launch_bounds__(256) void k_attn(
    const short* __restrict__ Qh, const short* __restrict__ Ql,
    const short* __restrict__ Kh, const short* __restrict__ Kl,
    const f16* __restrict__ Vm, f16* __restrict__ Om) {
  constexpr int S = 1024, DH = 64;
  const int p = blockIdx.y;
  const int q0 = blockIdx.x * 16;
  const size_t pb = (size_t)p * S * DH;
  const short* Qhp = Qh + pb;
  const short* Qlp = Ql + pb;
  const short* Khp = Kh + pb;
  const short* Klp = Kl + pb;
  const f16* Vp = Vm + pb;
  f16* Op = Om + pb;

  const int tid = threadIdx.x;
  const int w = tid >> 6;
  const int lane = tid & 63;
  const int l15 = lane & 15, lg = lane >> 4;

  __shared__ f16 Pl[16][1032];        // 33 KB, stride 2064B -> 2-way alias
  __shared__ f16 VT[64][72];          // 9 KB transposed V chunk
  __shared__ float redbuf[3][4][16];  // [sum,max,den][wave][row]

  // ---- phase 1: scores (split bf16: Qh@Kh + Qh@Kl + Ql@Kh) ----
  const size_t qoff = (size_t)(q0 + l15) * DH + lg * 8;
  bf16x8 aq0h = *(const bf16x8*)(Qhp + qoff);
  bf16x8 aq0l = *(const bf16x8*)(Qlp + qoff);
  bf16x8 aq1h = *(const bf16x8*)(Qhp + qoff + 32);
  bf16x8 aq1l = *(const bf16x8*)(Qlp + qoff + 32);
  const f32x4 fzero = {0.f, 0.f, 0.f, 0.f};
  f32x4 acc[16];
#pragma unroll
  for (int i = 0; i < 16; ++i) acc[i] = fzero;
  const int kb = w * 256;
#pragma unroll 4
  for (int n16 = 0; n16 < 16; ++n16) {
    const size_t ko = (size_t)(kb + n16 * 16 + l15) * DH + lg * 8;
    bf16x8 b0h = *(const bf16x8*)(Khp + ko);
    bf16x8 b0l = *(const bf16x8*)(Klp + ko);
    bf16x8 b1h = *(const bf16x8*)(Khp + ko + 32);
    bf16x8 b1l = *(const bf16x8*)(Klp + ko + 32);
    acc[n16] = MFMAB16(aq0h, b0h, acc[n16]);
    acc[n16] = MFMAB16(aq1h, b1h, acc[n16]);
    acc[n16] = MFMAB16(aq0h, b0l, acc[n16]);
    acc[n16] = MFMAB16(aq0l, b0h, acc[n16]);
    acc[n16] = MFMAB16(aq1h, b1l, acc[n16]);
    acc[n16] = MFMAB16(aq1l, b1h, acc[n16]);
  }
  // lane holds rows lg*4+r, cols kb + n16*16 + l15
  float psum[4], pmax[4];
#pragma unroll
  for (int r = 0; r < 4; ++r) { psum[r] = 0.f; pmax[r] = -1e30f; }
#pragma unroll
  for (int i = 0; i < 16; ++i)
#pragma unroll
    for (int r = 0; r < 4; ++r) {
      float v = acc[i][r] * kNorm;
      acc[i][r] = v;
      psum[r] += v;
      pmax[r] = fmaxf(pmax[r], v);
    }
#pragma unroll
  for (int off = 1; off < 16; off <<= 1)
#pragma unroll
    for (int r = 0; r < 4; ++r) {
      psum[r] += __shfl_xor(psum[r], off);
      pmax[r] = fmaxf(pmax[r], __shfl_xor(pmax[r], off));
    }
  if (l15 == 0)
#pragma unroll
    for (int r = 0; r < 4; ++r) {
      redbuf[0][w][lg * 4 + r] = psum[r];
      redbuf[1][w][lg * 4 + r] = pmax[r];
    }
  __syncthreads();
  float mean[4], mx[4];
#pragma unroll
  for (int r = 0; r < 4; ++r) {
    const int row = lg * 4 + r;
    float s = redbuf[0][0][row] + redbuf[0][1][row] + redbuf[0][2][row] +
              redbuf[0][3][row];
    float m = fmaxf(fmaxf(redbuf[1][0][row], redbuf[1][1][row]),
                    fmaxf(redbuf[1][2][row], redbuf[1][3][row]));
    mean[r] = s * (1.f / 1024.f);
    mx[r] = m;
  }
  float den[4] = {0.f, 0.f, 0.f, 0.f};
#pragma unroll
  for (int i = 0; i < 16; ++i)
#pragma unroll
    for (int r = 0; r < 4; ++r) {
      float v = acc[i][r];
      float e = (v > mean[r]) ? __expf(v - mx[r]) : 0.f;
      acc[i][r] = e;
      den[r] += e;
    }
#pragma unroll
  for (int off = 1; off < 16; off <<= 1)
#pragma unroll
    for (int r = 0; r < 4; ++r) den[r] += __shfl_xor(den[r], off);
  if (l15 == 0)
#pragma unroll
    for (int r = 0; r < 4; ++r) redbuf[2][w][lg * 4 + r] = den[r];
  __syncthreads();
  float inv[4];
#pragma unroll
  for (int r = 0; r < 4; ++r) {
    const int row = lg * 4 + r;
    inv[r] = 1.f / (redbuf[2][0][row] + redbuf[2][1][row] + redbuf[2][2][row] +
                    redbuf[2][3][row]);
  }
#pragma unroll
  for (int i = 0; i < 16; ++i)
#pragma unroll
    for (int r = 0; r < 4; ++r)
      Pl[lg * 4 + r][kb + i * 16 + l15] = (f16)(acc[i][r] * inv[r]);
  __syncthreads();

  // ---- phase 2: O = P @ V (fp16) ----
  f32x4 oacc = fzero;
  const int vkr = tid >> 2;        // key within 64-chunk
  const int vd0 = (tid & 3) * 16;  // dim slice
  for (int c = 0; c < S; c += 64) {
    f16x8 v0 = *(const f16x8*)(Vp + (size_t)(c + vkr) * DH + vd0);
    f16x8 v1 = *(const f16x8*)(Vp + (size_t)(c + vkr) * DH + vd0 + 8);
#pragma unroll
    for (int j = 0; j < 8; ++j) {
      VT[vd0 + j][vkr] = v0[j];
      VT[vd0 + 8 + j][vkr] = v1[j];
    }
    __syncthreads();
#pragma unroll
    for (int h = 0; h < 2; ++h) {
      f16x8 pa = *(const f16x8*)&Pl[l15][c + h * 32 + lg * 8];
      f16x8 vb = *(const f16x8*)&VT[w * 16 + l15][h * 32 + lg * 8];
      oacc = MFMA16(pa, vb, oacc);
    }
    __syncthreads();
  }
#pragma unroll
  for (int r = 0; r < 4; ++r)
    Op[(size_t)(q0 + lg * 4 + r) * DH + w * 16 + l15] = (f16)oacc[r];
}

// ------------------------------- launcher ----------------------------------
extern "C" void kernel_launch(void* const* d_in, const int* in_sizes, int n_in,
                              void* d_out, int out_size, void* d_ws,
                              size_t ws_size, hipStream_t stream) {
  const float* x = (const float*)d_in[0];
  const float* y = (const float*)d_in[1];
  const float* qw = (const float*)d_in[2];
  const float* qb = (const float*)d_in[3];
  const float* kw = (const float*)d_in[4];
  const float* kbias = (const float*)d_in[5];
  const float* vw = (const float*)d_in[6];
  const float* vb = (const float*)d_in[7];
  const float* ow = (const float*)d_in[8];
  const float* ob = (const float*)d_in[9];
  float* out = (float*)d_out;

  char* ws = (char*)d_ws;
  const size_t WT_B = 512ull * 512 * 2;    // 512 KB
  const size_t MAT_B = 8192ull * 512 * 2;  // 8 MB
  short* qwhT = (short*)(ws + 0 * WT_B);
  short* qwlT = (short*)(ws + 1 * WT_B);
  short* kwhT = (short*)(ws + 2 * WT_B);
  short* kwlT = (short*)(ws + 3 * WT_B);
  f16* vwT = (f16*)(ws + 4 * WT_B);
  f16* owT = (f16*)(ws + 5 * WT_B);
  char* mats = ws + 6 * WT_B;
  short* Qh = (short*)(mats + 0 * MAT_B);
  short* Ql = (short*)(mats + 1 * MAT_B);
  short* Kh = (short*)(mats + 2 * MAT_B);
  short* Kl = (short*)(mats + 3 * MAT_B);
  f16* Vm = (f16*)(mats + 4 * MAT_B);
  f16* Om = (f16*)(mats + 5 * MAT_B);  // total 51 MB

  hipLaunchKernelGGL(k_wt, dim3(16, 16, 4), dim3(32, 8), 0, stream, qw, kw, vw,
                     ow, qwhT, qwlT, kwhT, kwlT, vwT, owT);
  hipLaunchKernelGGL(k_gemm_qk, dim3(4, 64, 2), dim3(256), 0, stream, x, y,
                     qwhT, qwlT, kwhT, kwlT, qb, kbias, Qh, Ql, Kh, Kl);
  hipLaunchKernelGGL(k_gemm_v, dim3(4, 64), dim3(256), 0, stream, y, vwT, vb,
                     Vm);
  hipLaunchKernelGGL(k_attn, dim3(64, 64), dim3(256), 0, stream, Qh, Ql, Kh,
                     Kl, Vm, Om);
  hipLaunchKernelGGL(k_gemm_out, dim3(4, 64), dim3(256), 0, stream, Om, owT,
                     ob, out);
}

// Round 3
// 279.366 us; speedup vs baseline: 1.5521x; 1.5521x over previous
//
#include <hip/hip_runtime.h>
#include <hip/hip_bf16.h>
#include <hip/hip_fp16.h>

// ---------------------------------------------------------------------------
// Multihead attention with flat-reshape head split + mean-threshold mask.
//   B=8 S=1024 D=512 H=8 -> 64 independent attention problems of (1024 x 64);
//   problem (h,b) = 128 consecutive rows of the 8192x512 projected matrix
//   reinterpreted as 1024x64.
// Precision: Q/K path 3-term bf16 split (projection GEMM and QK^T) ->
//   fp32-accurate scores (mean-threshold mask flips ~0.02/row).
//   V / P / O / out-GEMM fp16. Round-2 absmax 3.4e-3 vs 6.05e-3 threshold.
// Round-3 changes (perf only, numerics identical):
//   1. k_attn phase-1 MFMA loop FULLY unrolled (was "#pragma unroll 4" ->
//      runtime-indexed acc[16] -> scratch spill -> ~1 GB HBM writes/dispatch).
//   2. V pre-transposed once globally (k_vtr) -> phase 2 reads V^T from
//      global (L2-resident); removes per-block LDS V transpose (the 29M
//      bank conflicts) and its syncthreads.
// ---------------------------------------------------------------------------

typedef _Float16 f16;
typedef __attribute__((ext_vector_type(8))) _Float16 f16x8;
typedef __attribute__((ext_vector_type(8))) short bf16x8;
typedef __attribute__((ext_vector_type(4))) float f32x4;

#define MFMA16(a, b, c) __builtin_amdgcn_mfma_f32_16x16x32_f16((a), (b), (c), 0, 0, 0)
#define MFMAB16(a, b, c) __builtin_amdgcn_mfma_f32_16x16x32_bf16((a), (b), (c), 0, 0, 0)

__constant__ const float kNorm = 0.04419417382415922f;  // 1/sqrt(512)

// float -> (bf16 hi, bf16 lo) with RNE via __float2bfloat16
__device__ __forceinline__ void splitbf(float v, short& h, short& l) {
  unsigned short hu = __bfloat16_as_ushort(__float2bfloat16(v));
  h = (short)hu;
  float hf = __uint_as_float(((unsigned)hu) << 16);
  l = (short)__bfloat16_as_ushort(__float2bfloat16(v - hf));
}

// --------------------------- weight transpose+convert ----------------------
// W [512][512] f32 (k,n) -> WT [512][512] (n,k).  q,k: bf16 hi/lo; v,o: f16.
__global__ void k_wt(const float* __restrict__ w0, const float* __restrict__ w1,
                     const float* __restrict__ w2, const float* __restrict__ w3,
                     short* __restrict__ qh, short* __restrict__ ql,
                     short* __restrict__ kh, short* __restrict__ kl,
                     f16* __restrict__ vt, f16* __restrict__ ot) {
  const float* W;
  switch (blockIdx.z) {
    case 0: W = w0; break;
    case 1: W = w1; break;
    case 2: W = w2; break;
    default: W = w3; break;
  }
  __shared__ float t[32][33];
  int bx = blockIdx.x, by = blockIdx.y;
  int tx = threadIdx.x, ty = threadIdx.y;  // 32 x 8
#pragma unroll
  for (int i = 0; i < 32; i += 8)
    t[ty + i][tx] = W[(size_t)(by * 32 + ty + i) * 512 + bx * 32 + tx];
  __syncthreads();
#pragma unroll
  for (int i = 0; i < 32; i += 8) {
    size_t idx = (size_t)(bx * 32 + ty + i) * 512 + by * 32 + tx;
    float v = t[tx][ty + i];
    if (blockIdx.z < 2) {
      short h, l;
      splitbf(v, h, l);
      if (blockIdx.z == 0) { qh[idx] = h; ql[idx] = l; }
      else { kh[idx] = h; kl[idx] = l; }
    } else {
      if (blockIdx.z == 2) vt[idx] = (f16)v;
      else ot[idx] = (f16)v;
    }
  }
}

// ------------------------- plain fp16 GEMM body ----------------------------
// C[8192][512] = A[8192][512] @ WT^T + bias ; WT is [n][k] f16.
// 128x128 tile, BK=32, 256 threads = 4 waves 2x2, each wave 64x64.
template <typename AT, typename OT>
__device__ __forceinline__ void gemm_body(const AT* __restrict__ A,
                                          const f16* __restrict__ WT,
                                          const float* __restrict__ bias,
                                          OT* __restrict__ C, int m0, int n0) {
  __shared__ f16 As[128][40];  // +8 pad: stride 80B -> ~2-way bank alias (free)
  __shared__ f16 Bs[128][40];
  const int tid = threadIdx.x;
  const int wv = tid >> 6, lane = tid & 63;
  const int wm = wv >> 1, wn = wv & 1;
  const int l15 = lane & 15, lg = lane >> 4;
  const int sr = tid >> 1, sc = (tid & 1) * 16;

  const f32x4 fzero = {0.f, 0.f, 0.f, 0.f};
  f32x4 acc[4][4];
#pragma unroll
  for (int m = 0; m < 4; ++m)
#pragma unroll
    for (int n = 0; n < 4; ++n) acc[m][n] = fzero;

  for (int k0 = 0; k0 < 512; k0 += 32) {
    if constexpr (sizeof(AT) == 4) {  // fp32 source: convert during staging
      const float* src = (const float*)A + (size_t)(m0 + sr) * 512 + k0 + sc;
      float4 a0 = *(const float4*)(src + 0);
      float4 a1 = *(const float4*)(src + 4);
      float4 a2 = *(const float4*)(src + 8);
      float4 a3 = *(const float4*)(src + 12);
      f16* d = &As[sr][sc];
      d[0] = (f16)a0.x; d[1] = (f16)a0.y; d[2] = (f16)a0.z; d[3] = (f16)a0.w;
      d[4] = (f16)a1.x; d[5] = (f16)a1.y; d[6] = (f16)a1.z; d[7] = (f16)a1.w;
      d[8] = (f16)a2.x; d[9] = (f16)a2.y; d[10] = (f16)a2.z; d[11] = (f16)a2.w;
      d[12] = (f16)a3.x; d[13] = (f16)a3.y; d[14] = (f16)a3.z; d[15] = (f16)a3.w;
    } else {
      const f16* src = (const f16*)A + (size_t)(m0 + sr) * 512 + k0 + sc;
      *(f16x8*)&As[sr][sc] = *(const f16x8*)src;
      *(f16x8*)&As[sr][sc + 8] = *(const f16x8*)(src + 8);
    }
    {
      const f16* src = WT + (size_t)(n0 + sr) * 512 + k0 + sc;
      *(f16x8*)&Bs[sr][sc] = *(const f16x8*)src;
      *(f16x8*)&Bs[sr][sc + 8] = *(const f16x8*)(src + 8);
    }
    __syncthreads();
    f16x8 af[4], bf[4];
#pragma unroll
    for (int m = 0; m < 4; ++m)
      af[m] = *(const f16x8*)&As[wm * 64 + m * 16 + l15][lg * 8];
#pragma unroll
    for (int n = 0; n < 4; ++n)
      bf[n] = *(const f16x8*)&Bs[wn * 64 + n * 16 + l15][lg * 8];
#pragma unroll
    for (int m = 0; m < 4; ++m)
#pragma unroll
      for (int n = 0; n < 4; ++n) acc[m][n] = MFMA16(af[m], bf[n], acc[m][n]);
    __syncthreads();
  }
  // D row=(lane>>4)*4+r, col=lane&15 (m89-verified layout)
#pragma unroll
  for (int n = 0; n < 4; ++n) {
    const int col = n0 + wn * 64 + n * 16 + l15;
    const float b = bias[col];
#pragma unroll
    for (int m = 0; m < 4; ++m) {
      const int row = m0 + wm * 64 + m * 16 + lg * 4;
#pragma unroll
      for (int r = 0; r < 4; ++r) {
        float v = acc[m][n][r] + b;
        C[(size_t)(row + r) * 512 + col] = (OT)v;
      }
    }
  }
}

__global__ __launch_bounds__(256) void k_gemm_v(const float* __restrict__ y,
                                                const f16* __restrict__ vwT,
                                                const float* __restrict__ vb,
                                                f16* __restrict__ Vm) {
  gemm_body<float, f16>(y, vwT, vb, Vm, blockIdx.y * 128, blockIdx.x * 128);
}

__global__ __launch_bounds__(256) void k_gemm_out(const f16* __restrict__ Om,
                                                  const f16* __restrict__ owT,
                                                  const float* __restrict__ ob,
                                                  float* __restrict__ out) {
  gemm_body<f16, float>(Om, owT, ob, out, blockIdx.y * 128, blockIdx.x * 128);
}

// -------------------- split-bf16 GEMM for Q,K projections ------------------
__global__ __launch_bounds__(256) void k_gemm_qk(
    const float* __restrict__ x, const float* __restrict__ y,
    const short* __restrict__ qwh, const short* __restrict__ qwl,
    const short* __restrict__ kwh, const short* __restrict__ kwl,
    const float* __restrict__ qb, const float* __restrict__ kbias,
    short* __restrict__ Qh, short* __restrict__ Ql, short* __restrict__ Kh,
    short* __restrict__ Kl) {
  const float* A;
  const short *Wh, *Wl;
  const float* bias;
  short *Ch, *Cl;
  if (blockIdx.z == 0) { A = x; Wh = qwh; Wl = qwl; bias = qb; Ch = Qh; Cl = Ql; }
  else { A = y; Wh = kwh; Wl = kwl; bias = kbias; Ch = Kh; Cl = Kl; }
  const int m0 = blockIdx.y * 128, n0 = blockIdx.x * 128;

  __shared__ short Ah[128][40], Al[128][40];
  __shared__ short Bh[128][40], Bl[128][40];
  const int tid = threadIdx.x;
  const int wv = tid >> 6, lane = tid & 63;
  const int wm = wv >> 1, wn = wv & 1;
  const int l15 = lane & 15, lg = lane >> 4;
  const int sr = tid >> 1, sc = (tid & 1) * 16;

  const f32x4 fzero = {0.f, 0.f, 0.f, 0.f};
  f32x4 acc[4][4];
#pragma unroll
  for (int m = 0; m < 4; ++m)
#pragma unroll
    for (int n = 0; n < 4; ++n) acc[m][n] = fzero;

  for (int k0 = 0; k0 < 512; k0 += 32) {
    {
      const float* src = A + (size_t)(m0 + sr) * 512 + k0 + sc;
      float4 a0 = *(const float4*)(src + 0);
      float4 a1 = *(const float4*)(src + 4);
      float4 a2 = *(const float4*)(src + 8);
      float4 a3 = *(const float4*)(src + 12);
      short* dh = &Ah[sr][sc];
      short* dl = &Al[sr][sc];
      splitbf(a0.x, dh[0], dl[0]);   splitbf(a0.y, dh[1], dl[1]);
      splitbf(a0.z, dh[2], dl[2]);   splitbf(a0.w, dh[3], dl[3]);
      splitbf(a1.x, dh[4], dl[4]);   splitbf(a1.y, dh[5], dl[5]);
      splitbf(a1.z, dh[6], dl[6]);   splitbf(a1.w, dh[7], dl[7]);
      splitbf(a2.x, dh[8], dl[8]);   splitbf(a2.y, dh[9], dl[9]);
      splitbf(a2.z, dh[10], dl[10]); splitbf(a2.w, dh[11], dl[11]);
      splitbf(a3.x, dh[12], dl[12]); splitbf(a3.y, dh[13], dl[13]);
      splitbf(a3.z, dh[14], dl[14]); splitbf(a3.w, dh[15], dl[15]);
    }
    {
      const size_t o = (size_t)(n0 + sr) * 512 + k0 + sc;
      *(bf16x8*)&Bh[sr][sc] = *(const bf16x8*)(Wh + o);
      *(bf16x8*)&Bh[sr][sc + 8] = *(const bf16x8*)(Wh + o + 8);
      *(bf16x8*)&Bl[sr][sc] = *(const bf16x8*)(Wl + o);
      *(bf16x8*)&Bl[sr][sc + 8] = *(const bf16x8*)(Wl + o + 8);
    }
    __syncthreads();
    bf16x8 afh[4], afl[4], bfh[4], bfl[4];
#pragma unroll
    for (int m = 0; m < 4; ++m) {
      afh[m] = *(const bf16x8*)&Ah[wm * 64 + m * 16 + l15][lg * 8];
      afl[m] = *(const bf16x8*)&Al[wm * 64 + m * 16 + l15][lg * 8];
    }
#pragma unroll
    for (int n = 0; n < 4; ++n) {
      bfh[n] = *(const bf16x8*)&Bh[wn * 64 + n * 16 + l15][lg * 8];
      bfl[n] = *(const bf16x8*)&Bl[wn * 64 + n * 16 + l15][lg * 8];
    }
#pragma unroll
    for (int m = 0; m < 4; ++m)
#pragma unroll
      for (int n = 0; n < 4; ++n) {
        acc[m][n] = MFMAB16(afh[m], bfh[n], acc[m][n]);
        acc[m][n] = MFMAB16(afh[m], bfl[n], acc[m][n]);
        acc[m][n] = MFMAB16(afl[m], bfh[n], acc[m][n]);
      }
    __syncthreads();
  }
#pragma unroll
  for (int n = 0; n < 4; ++n) {
    const int col = n0 + wn * 64 + n * 16 + l15;
    const float b = bias[col];
#pragma unroll
    for (int m = 0; m < 4; ++m) {
      const int row = m0 + wm * 64 + m * 16 + lg * 4;
#pragma unroll
      for (int r = 0; r < 4; ++r) {
        float v = acc[m][n][r] + b;
        short h, l;
        splitbf(v, h, l);
        const size_t idx = (size_t)(row + r) * 512 + col;
        Ch[idx] = h;
        Cl[idx] = l;
      }
    }
  }
}

// ----------------------- V transpose (per problem) -------------------------
// Vm [8192][512] f16 -> Vt [64 problems][64 dh][1024 k] f16.
// Mapping (flat reshape): token t, col d -> p=t>>7, k=(t&127)*8+(d>>6), dh=d&63.
// So Vt[p][dh][j*8+g] = Vm[p*128+j][g*64+dh]: one source row j supplies the
// k-octet [j*8, j*8+8) for every dh -> coalesced f16x8 writes.
__global__ __launch_bounds__(256) void k_vtr(const f16* __restrict__ Vm,
                                             f16* __restrict__ Vt) {
  const int p = blockIdx.y;
  const int j0 = blockIdx.x * 16;  // 16 source rows per block
  __shared__ f16 L[16][520];       // 512 + 8 pad
  const int tid = threadIdx.x;
#pragma unroll
  for (int it = 0; it < 4; ++it) {
    int idx = it * 256 + tid;        // 1024 octets = 16 rows x 64
    int row = idx >> 6, oct = idx & 63;
    *(f16x8*)&L[row][oct * 8] =
        *(const f16x8*)&Vm[(size_t)(p * 128 + j0 + row) * 512 + oct * 8];
  }
  __syncthreads();
#pragma unroll
  for (int it = 0; it < 4; ++it) {
    int idx = it * 256 + tid;        // 1024 octets = 64 dh x 16 j
    int dh = idx >> 4, j = idx & 15;
    f16x8 v;
#pragma unroll
    for (int g = 0; g < 8; ++g) v[g] = L[j][g * 64 + dh];
    *(f16x8*)&Vt[((size_t)p * 64 + dh) * 1024 + (j0 + j) * 8] = v;
  }
}

// ------------------------------- attention ---------------------------------
// grid (64 q-tiles, 64 problems), 256 threads = 4 waves.
// Phase 1: wave w computes S[16 q][256 keys] via split-bf16 MFMA (6/tile),
//   fragments straight from global (K chunk is L2-resident). FULL unroll:
//   partial unroll made acc[] runtime-indexed -> scratch (round-2 lesson).
// Softmax: mean-threshold mask; global row max.
// Phase 2: O = P @ V via Vt read straight from global (L2-resident).
__global__ __launch_bounds__(256) void k_attn(
    const short* __restrict__ Qh, const short* __restrict__ Ql,
    const short* __restrict__ Kh, const short* __restrict__ Kl,
    const f16* __restrict__ Vt, f16* __restrict__ Om) {
  constexpr int S = 1024, DH = 64;
  const int p = blockIdx.y;
  const int q0 = blockIdx.x * 16;
  const size_t pb = (size_t)p * S * DH;
  const short* Qhp = Qh + pb;
  const short* Qlp = Ql + pb;
  const short* Khp = Kh + pb;
  const short* Klp = Kl + pb;
  f16* Op = Om + pb;

  const int tid = threadIdx.x;
  const int w = tid >> 6;
  const int lane = tid & 63;
  const int l15 = lane & 15, lg = lane >> 4;

  __shared__ __align__(16) f16 Pl[16][1032];  // 33 KB, stride 2064B
  __shared__ float redbuf[3][4][16];          // [sum,max,den][wave][row]

  // ---- phase 1: scores (split bf16: Qh@Kh + Qh@Kl + Ql@Kh) ----
  const size_t qoff = (size_t)(q0 + l15) * DH + lg * 8;
  bf16x8 aq0h = *(const bf16x8*)(Qhp + qoff);
  bf16x8 aq0l = *(const bf16x8*)(Qlp + qoff);
  bf16x8 aq1h = *(const bf16x8*)(Qhp + qoff + 32);
  bf16x8 aq1l = *(const bf16x8*)(Qlp + qoff + 32);
  const f32x4 fzero = {0.f, 0.f, 0.f, 0.f};
  f32x4 acc[16];
#pragma unroll
  for (int i = 0; i < 16; ++i) acc[i] = fzero;
  const int kb = w * 256;
#pragma unroll  // FULL unroll: keeps acc[] indices compile-time (rule #20)
  for (int n16 = 0; n16 < 16; ++n16) {
    const size_t ko = (size_t)(kb + n16 * 16 + l15) * DH + lg * 8;
    bf16x8 b0h = *(const bf16x8*)(Khp + ko);
    bf16x8 b0l = *(const bf16x8*)(Klp + ko);
    bf16x8 b1h = *(const bf16x8*)(Khp + ko + 32);
    bf16x8 b1l = *(const bf16x8*)(Klp + ko + 32);
    acc[n16] = MFMAB16(aq0h, b0h, acc[n16]);
    acc[n16] = MFMAB16(aq1h, b1h, acc[n16]);
    acc[n16] = MFMAB16(aq0h, b0l, acc[n16]);
    acc[n16] = MFMAB16(aq0l, b0h, acc[n16]);
    acc[n16] = MFMAB16(aq1h, b1l, acc[n16]);
    acc[n16] = MFMAB16(aq1l, b1h, acc[n16]);
  }
  // lane holds rows lg*4+r, cols kb + n16*16 + l15
  float psum[4], pmax[4];
#pragma unroll
  for (int r = 0; r < 4; ++r) { psum[r] = 0.f; pmax[r] = -1e30f; }
#pragma unroll
  for (int i = 0; i < 16; ++i)
#pragma unroll
    for (int r = 0; r < 4; ++r) {
      float v = acc[i][r] * kNorm;
      acc[i][r] = v;
      psum[r] += v;
      pmax[r] = fmaxf(pmax[r], v);
    }
#pragma unroll
  for (int off = 1; off < 16; off <<= 1)
#pragma unroll
    for (int r = 0; r < 4; ++r) {
      psum[r] += __shfl_xor(psum[r], off);
      pmax[r] = fmaxf(pmax[r], __shfl_xor(pmax[r], off));
    }
  if (l15 == 0)
#pragma unroll
    for (int r = 0; r < 4; ++r) {
      redbuf[0][w][lg * 4 + r] = psum[r];
      redbuf[1][w][lg * 4 + r] = pmax[r];
    }
  __syncthreads();
  float mean[4], mx[4];
#pragma unroll
  for (int r = 0; r < 4; ++r) {
    const int row = lg * 4 + r;
    float s = redbuf[0][0][row] + redbuf[0][1][row] + redbuf[0][2][row] +
              redbuf[0][3][row];
    float m = fmaxf(fmaxf(redbuf[1][0][row], redbuf[1][1][row]),
                    fmaxf(redbuf[1][2][row], redbuf[1][3][row]));
    mean[r] = s * (1.f / 1024.f);
    mx[r] = m;
  }
  float den[4] = {0.f, 0.f, 0.f, 0.f};
#pragma unroll
  for (int i = 0; i < 16; ++i)
#pragma unroll
    for (int r = 0; r < 4; ++r) {
      float v = acc[i][r];
      float e = (v > mean[r]) ? __expf(v - mx[r]) : 0.f;
      acc[i][r] = e;
      den[r] += e;
    }
#pragma unroll
  for (int off = 1; off < 16; off <<= 1)
#pragma unroll
    for (int r = 0; r < 4; ++r) den[r] += __shfl_xor(den[r], off);
  if (l15 == 0)
#pragma unroll
    for (int r = 0; r < 4; ++r) redbuf[2][w][lg * 4 + r] = den[r];
  __syncthreads();
  float inv[4];
#pragma unroll
  for (int r = 0; r < 4; ++r) {
    const int row = lg * 4 + r;
    inv[r] = 1.f / (redbuf[2][0][row] + redbuf[2][1][row] + redbuf[2][2][row] +
                    redbuf[2][3][row]);
  }
#pragma unroll
  for (int i = 0; i < 16; ++i)
#pragma unroll
    for (int r = 0; r < 4; ++r)
      Pl[lg * 4 + r][kb + i * 16 + l15] = (f16)(acc[i][r] * inv[r]);
  __syncthreads();

  // ---- phase 2: O = P @ V, V^T straight from global (L2-resident) ----
  f32x4 oacc = fzero;
  const f16* Vtp = Vt + ((size_t)p * 64 + w * 16 + l15) * 1024;
#pragma unroll
  for (int kk = 0; kk < S; kk += 32) {
    f16x8 pa = *(const f16x8*)&Pl[l15][kk + lg * 8];
    f16x8 vb = *(const f16x8*)(Vtp + kk + lg * 8);
    oacc = MFMA16(pa, vb, oacc);
  }
#pragma unroll
  for (int r = 0; r < 4; ++r)
    Op[(size_t)(q0 + lg * 4 + r) * DH + w * 16 + l15] = (f16)oacc[r];
}

// ------------------------------- launcher ----------------------------------
extern "C" void kernel_launch(void* const* d_in, const int* in_sizes, int n_in,
                              void* d_out, int out_size, void* d_ws,
                              size_t ws_size, hipStream_t stream) {
  const float* x = (const float*)d_in[0];
  const float* y = (const float*)d_in[1];
  const float* qw = (const float*)d_in[2];
  const float* qb = (const float*)d_in[3];
  const float* kw = (const float*)d_in[4];
  const float* kbias = (const float*)d_in[5];
  const float* vw = (const float*)d_in[6];
  const float* vb = (const float*)d_in[7];
  const float* ow = (const float*)d_in[8];
  const float* ob = (const float*)d_in[9];
  float* out = (float*)d_out;

  char* ws = (char*)d_ws;
  const size_t WT_B = 512ull * 512 * 2;    // 512 KB
  const size_t MAT_B = 8192ull * 512 * 2;  // 8 MB
  short* qwhT = (short*)(ws + 0 * WT_B);
  short* qwlT = (short*)(ws + 1 * WT_B);
  short* kwhT = (short*)(ws + 2 * WT_B);
  short* kwlT = (short*)(ws + 3 * WT_B);
  f16* vwT = (f16*)(ws + 4 * WT_B);
  f16* owT = (f16*)(ws + 5 * WT_B);
  char* mats = ws + 6 * WT_B;
  short* Qh = (short*)(mats + 0 * MAT_B);
  short* Ql = (short*)(mats + 1 * MAT_B);
  short* Kh = (short*)(mats + 2 * MAT_B);
  short* Kl = (short*)(mats + 3 * MAT_B);
  f16* Vm = (f16*)(mats + 4 * MAT_B);
  f16* Om = (f16*)(mats + 5 * MAT_B);
  f16* Vtr = (f16*)(mats + 6 * MAT_B);  // total 59 MB

  hipLaunchKernelGGL(k_wt, dim3(16, 16, 4), dim3(32, 8), 0, stream, qw, kw, vw,
                     ow, qwhT, qwlT, kwhT, kwlT, vwT, owT);
  hipLaunchKernelGGL(k_gemm_qk, dim3(4, 64, 2), dim3(256), 0, stream, x, y,
                     qwhT, qwlT, kwhT, kwlT, qb, kbias, Qh, Ql, Kh, Kl);
  hipLaunchKernelGGL(k_gemm_v, dim3(4, 64), dim3(256), 0, stream, y, vwT, vb,
                     Vm);
  hipLaunchKernelGGL(k_vtr, dim3(8, 64), dim3(256), 0, stream, Vm, Vtr);
  hipLaunchKernelGGL(k_attn, dim3(64, 64), dim3(256), 0, stream, Qh, Ql, Kh,
                     Kl, Vtr, Om);
  hipLaunchKernelGGL(k_gemm_out, dim3(4, 64), dim3(256), 0, stream, Om, owT,
                     ob, out);
}